// Round 12
// baseline (46.162 us; speedup 1.0000x reference)
//
#include <hip/hip_runtime.h>

#define N_SEG 256
#define HIDDEN 512
#define CHUNKS 16
#define NB (N_SEG * CHUNKS)   // 4096 blocks
#define WIN 4096
#define NEG_INF (-__builtin_inff())

// Guarded windowed lower_bound: window +-WIN around the arithmetic expectation
// n*key/256; one guard probe on each edge, full-range fallback if it fails.
// Correct for ANY sorted batch; 13 search rounds instead of 17, L2-hot for
// the 15 sibling blocks that share the same key.
__device__ __forceinline__ int lower_bound_win(const int* __restrict__ batch,
                                               int n, int key) {
    int es = (int)(((long long)n * key) >> 8);
    int wlo = es - WIN; if (wlo < 0) wlo = 0;
    int whi = es + WIN; if (whi > n) whi = n;
    bool ok = (wlo == 0 || batch[wlo - 1] < key) && (whi == n || batch[whi] >= key);
    int lo = ok ? wlo : 0;
    int hi = ok ? whi : n;
    while (lo < hi) { int mid = (lo + hi) >> 1; if (batch[mid] < key) lo = mid + 1; else hi = mid; }
    return lo;
}

// One block per (segment, chunk): in-fused windowed bounds (two independent
// 13-round chains, ILP-overlapped; W loads issued first), c-th 1/16 slice,
// 4 waves interleaved (one sequential ~8KB-burst stream), online softmax +
// depth-1 prefetch, LDS merge of the 4 waves, one partial (m,d,acc[512]) at
// slot = blockIdx.x.
__global__ __launch_bounds__(256) void fused_kernel(
    const float* __restrict__ x, const float* __restrict__ W,
    const int* __restrict__ batch,
    float* __restrict__ pacc, float* __restrict__ pm, float* __restrict__ pd,
    int n) {
    int b = blockIdx.x;
    int s = b >> 4, c = b & 15;
    int t = threadIdx.x, lane = t & 63, w = t >> 6;

    // independent loads first
    float4 w0 = *(const float4*)(W + lane * 8);
    float4 w1 = *(const float4*)(W + lane * 8 + 4);

    int ss = lower_bound_win(batch, n, s);
    int se = lower_bound_win(batch, n, s + 1);
    int len = se - ss;
    int st = ss + (int)(((long long)len * c) >> 4);
    int en = ss + (int)(((long long)len * (c + 1)) >> 4);

    if (st >= en) {  // empty chunk: neutral partial
        if (t == 0) { pm[b] = NEG_INF; pd[b] = 0.0f; }
        for (int j = t; j < HIDDEN; j += 256) pacc[(size_t)b * HIDDEN + j] = 0.0f;
        return;
    }

    float m = NEG_INF, d = 0.0f;
    float acc[8] = {0, 0, 0, 0, 0, 0, 0, 0};

    int i = st + w;
    bool have = i < en;   // wave-uniform
    float4 a0, a1;
    if (have) {
        const float* xr = x + (size_t)i * HIDDEN + lane * 8;
        a0 = *(const float4*)xr; a1 = *(const float4*)(xr + 4);
    }
    while (have) {
        int inext = i + 4;
        bool hnext = inext < en;
        float4 b0, b1;
        if (hnext) {  // depth-1 prefetch of next owned row
            const float* xr = x + (size_t)inext * HIDDEN + lane * 8;
            b0 = *(const float4*)xr; b1 = *(const float4*)(xr + 4);
        }
        float g = a0.x * w0.x + a0.y * w0.y + a0.z * w0.z + a0.w * w0.w
                + a1.x * w1.x + a1.y * w1.y + a1.z * w1.z + a1.w * w1.w;
        #pragma unroll
        for (int off = 32; off; off >>= 1) g += __shfl_xor(g, off, 64);
        float mn = fmaxf(m, g);
        float scale = __expf(m - mn);  // 0 on first row (m=-inf), 1 if max unchanged
        float p = __expf(g - mn);
        d = d * scale + p;
        acc[0] = acc[0] * scale + p * a0.x;  acc[1] = acc[1] * scale + p * a0.y;
        acc[2] = acc[2] * scale + p * a0.z;  acc[3] = acc[3] * scale + p * a0.w;
        acc[4] = acc[4] * scale + p * a1.x;  acc[5] = acc[5] * scale + p * a1.y;
        acc[6] = acc[6] * scale + p * a1.z;  acc[7] = acc[7] * scale + p * a1.w;
        m = mn;
        a0 = b0; a1 = b1; i = inext; have = hnext;
    }

    // block-level softmax merge of the 4 waves via LDS
    __shared__ float sm[4], sd[4];
    __shared__ float sacc[4][HIDDEN];  // 8 KB
    if (lane == 0) sm[w] = m;
    __syncthreads();
    float M = fmaxf(fmaxf(sm[0], sm[1]), fmaxf(sm[2], sm[3]));  // wave 0 nonempty -> finite
    float scale = (m == NEG_INF) ? 0.0f : __expf(m - M);
    if (lane == 0) sd[w] = d * scale;
    #pragma unroll
    for (int j = 0; j < 8; ++j) sacc[w][lane * 8 + j] = acc[j] * scale;
    __syncthreads();
    if (t == 0) { pm[b] = M; pd[b] = sd[0] + sd[1] + sd[2] + sd[3]; }
    for (int j = t; j < HIDDEN; j += 256)
        pacc[(size_t)b * HIDDEN + j] = sacc[0][j] + sacc[1][j] + sacc[2][j] + sacc[3][j];
}

// 4 blocks per segment (128 columns each): softmax-merge the segment's 16
// fixed slots; per thread 16 independent pacc loads, one wait.
__global__ __launch_bounds__(128) void merge_kernel(
    const float* __restrict__ pacc, const float* __restrict__ pm,
    const float* __restrict__ pd, float* __restrict__ out) {
    int s = blockIdx.x >> 2;
    int col = ((blockIdx.x & 3) << 7) + threadIdx.x;
    int k0 = s * CHUNKS;
    float M = NEG_INF;
    #pragma unroll
    for (int k = 0; k < CHUNKS; ++k) M = fmaxf(M, pm[k0 + k]);
    float wts[CHUNKS];
    float D = 0.0f;
    #pragma unroll
    for (int k = 0; k < CHUNKS; ++k) {
        float mk = pm[k0 + k];
        float wk = (mk == NEG_INF) ? 0.0f : __expf(mk - M);  // also guards empty segment
        wts[k] = wk;
        D += pd[k0 + k] * wk;
    }
    float invD = 1.0f / (D + 1e-16f);
    float num = 0.0f;
    #pragma unroll
    for (int k = 0; k < CHUNKS; ++k)
        num += pacc[(size_t)(k0 + k) * HIDDEN + col] * wts[k];
    out[s * HIDDEN + col] = num * invD;  // empty segment -> 0
}

extern "C" void kernel_launch(void* const* d_in, const int* in_sizes, int n_in,
                              void* d_out, int out_size, void* d_ws, size_t ws_size,
                              hipStream_t stream) {
    const float* x     = (const float*)d_in[0];
    const int*   batch = (const int*)d_in[1];
    const float* W     = (const float*)d_in[2];
    int n = in_sizes[1];
    float* out = (float*)d_out;

    // ws: pacc[NB*512] (16B-aligned first) | pm[NB] | pd[NB]
    float* pacc = (float*)d_ws;
    float* pm   = pacc + (size_t)NB * HIDDEN;
    float* pd   = pm + NB;

    fused_kernel<<<NB, 256, 0, stream>>>(x, W, batch, pacc, pm, pd, n);
    merge_kernel<<<N_SEG * 4, 128, 0, stream>>>(pacc, pm, pd, out);
}